// Round 3
// baseline (6954.119 us; speedup 1.0000x reference)
//
#include <hip/hip_runtime.h>
#include <hip/hip_bf16.h>

// Problem constants
#define T_SEQ 3072
#define DIM 2048
#define NH 16
#define QLORA 1536
#define KVLORA 512
#define NOPE 128
#define ROPE 64
#define VDIM 128
#define HD 192          // NOPE+ROPE
#define SCALE 0.07216878364870323f  // 192^-0.5

// ---------------- helpers ----------------
__device__ inline float wave_reduce_sum(float v) {
    #pragma unroll
    for (int off = 32; off > 0; off >>= 1) v += __shfl_down(v, off);
    return v;
}

__device__ inline float block_reduce_sum_256(float v) {
    __shared__ float red[4];
    int lane = threadIdx.x & 63, w = threadIdx.x >> 6;
    v = wave_reduce_sum(v);
    if (lane == 0) red[w] = v;
    __syncthreads();
    if (threadIdx.x == 0) red[0] = red[0] + red[1] + red[2] + red[3];
    __syncthreads();
    return red[0];
}

// ---------------- GEMM: C[M,N] = A[M,K] x B[K,N], all fp32 ----------------
// 128x128 tile, BK=16, 256 threads, 8x8 micro-tile per thread.
__global__ __launch_bounds__(256) void gemm128(
    const float* __restrict__ A, const float* __restrict__ B,
    float* __restrict__ C, int M, int N, int K)
{
    __shared__ float As[16][132];   // k-major: As[k][m]
    __shared__ float Bs[16][132];   // Bs[k][n]
    int tid = threadIdx.x;
    int tx = tid & 15, ty = tid >> 4;
    int bm = blockIdx.y * 128, bn = blockIdx.x * 128;

    float acc[8][8];
    #pragma unroll
    for (int i = 0; i < 8; ++i)
        #pragma unroll
        for (int j = 0; j < 8; ++j) acc[i][j] = 0.f;

    for (int k0 = 0; k0 < K; k0 += 16) {
        #pragma unroll
        for (int l = 0; l < 8; ++l) {
            int i = tid + l * 256;
            int rr = i >> 4, cc = i & 15;
            As[cc][rr] = A[(size_t)(bm + rr) * K + k0 + cc];
        }
        #pragma unroll
        for (int l = 0; l < 8; ++l) {
            int i = tid + l * 256;
            int rr = i >> 7, cc = i & 127;
            int col = bn + cc;
            Bs[rr][cc] = (col < N) ? B[(size_t)(k0 + rr) * N + col] : 0.f;
        }
        __syncthreads();
        #pragma unroll
        for (int kk = 0; kk < 16; ++kk) {
            float a[8], b[8];
            *(float4*)&a[0] = *(const float4*)&As[kk][ty * 8];
            *(float4*)&a[4] = *(const float4*)&As[kk][ty * 8 + 4];
            *(float4*)&b[0] = *(const float4*)&Bs[kk][tx * 8];
            *(float4*)&b[4] = *(const float4*)&Bs[kk][tx * 8 + 4];
            #pragma unroll
            for (int i = 0; i < 8; ++i)
                #pragma unroll
                for (int j = 0; j < 8; ++j)
                    acc[i][j] += a[i] * b[j];
        }
        __syncthreads();
    }
    #pragma unroll
    for (int i = 0; i < 8; ++i) {
        int row = bm + ty * 8 + i;
        #pragma unroll
        for (int j = 0; j < 8; ++j) {
            int col = bn + tx * 8 + j;
            if (col < N) C[(size_t)row * N + col] = acc[i][j];
        }
    }
}

// ---------------- rmsnorm in-place over rows ----------------
__global__ __launch_bounds__(256) void rmsnorm_rows(
    float* __restrict__ X, const float* __restrict__ w, int N)
{
    int row = blockIdx.x;
    float* x = X + (size_t)row * N;
    float ss = 0.f;
    for (int i = threadIdx.x; i < N; i += 256) { float v = x[i]; ss += v * v; }
    ss = block_reduce_sum_256(ss);
    float sc = rsqrtf(ss / (float)N + 1e-6f);
    for (int i = threadIdx.x; i < N; i += 256)
        x[i] = x[i] * sc * w[i];
}

// ---------------- kv post: rmsnorm(c_kv) -> ckvn ; rope(k_rope_raw) -> kr ----------------
__global__ __launch_bounds__(256) void kv_post(
    const float* __restrict__ kvd, const float* __restrict__ w,
    const float* __restrict__ freqs,
    float* __restrict__ ckvn, float* __restrict__ kr)
{
    int row = blockIdx.x;
    const float* src = kvd + (size_t)row * (KVLORA + ROPE);
    float ss = 0.f;
    for (int i = threadIdx.x; i < KVLORA; i += 256) { float v = src[i]; ss += v * v; }
    ss = block_reduce_sum_256(ss);
    float sc = rsqrtf(ss / (float)KVLORA + 1e-6f);
    for (int i = threadIdx.x; i < KVLORA; i += 256)
        ckvn[(size_t)row * KVLORA + i] = src[i] * sc * w[i];
    if (threadIdx.x < 32) {
        int i = threadIdx.x;
        float f = freqs[row * 32 + i];
        float c = cosf(f), s = sinf(f);
        float x1 = src[KVLORA + 2 * i], x2 = src[KVLORA + 2 * i + 1];
        kr[(size_t)row * ROPE + 2 * i]     = x1 * c - x2 * s;
        kr[(size_t)row * ROPE + 2 * i + 1] = x1 * s + x2 * c;
    }
}

// ---------------- rope on q_rope in-place: qr [T][NH*64] ----------------
__global__ void rope_q(float* __restrict__ qr, const float* __restrict__ freqs) {
    int idx = blockIdx.x * 256 + threadIdx.x;   // T*NH*32 pairs
    if (idx >= T_SEQ * NH * 32) return;
    int t = idx >> 9;          // /(NH*32)
    int rem = idx & 511;
    int h = rem >> 5;
    int i = rem & 31;
    float f = freqs[t * 32 + i];
    float c = cosf(f), s = sinf(f);
    float* p = qr + (size_t)t * (NH * ROPE) + h * ROPE + 2 * i;
    float x1 = p[0], x2 = p[1];
    p[0] = x1 * c - x2 * s;
    p[1] = x1 * s + x2 * c;
}

// ---------------- flash attention (causal) ----------------
// grid: (96 q-tiles, 16 heads), block 256.
// Q tile 32x192 fp32; K tile 16x192; V tile 16x128; online softmax; O in regs.
// Static LDS ~49KB (under the 64KB/workgroup bound).
__global__ __launch_bounds__(256) void attn_kernel(
    const float* __restrict__ QN, const float* __restrict__ QR,
    const float* __restrict__ KVU, const float* __restrict__ KR,
    float* __restrict__ AO)
{
    __shared__ float Qs[32][196];
    __shared__ float Ks[16][196];
    __shared__ float Vs[16][132];
    __shared__ float Sb[32][20];
    __shared__ float mrow[32], lrow[32], arow[32];

    int tid = threadIdx.x;
    int qt = blockIdx.x, h = blockIdx.y;

    for (int i = tid; i < 32 * HD; i += 256) {
        int r = i / HD, d = i % HD;
        int t = qt * 32 + r;
        Qs[r][d] = (d < NOPE) ? QN[(size_t)t * (NH * NOPE) + h * NOPE + d]
                              : QR[(size_t)t * (NH * ROPE) + h * ROPE + (d - NOPE)];
    }
    if (tid < 32) { mrow[tid] = -3e38f; lrow[tid] = 0.f; }

    float o[16];
    #pragma unroll
    for (int j = 0; j < 16; ++j) o[j] = 0.f;

    int r  = tid >> 3;           // 0..31 (q row in tile)
    int c0 = (tid & 7) * 2;      // 2 score cols per thread
    int d0 = (tid & 7) * 16;     // 16 V dims per thread
    __syncthreads();

    int ktmax = 2 * qt + 1;      // 16-wide K tiles covering [0, 32*qt+32)
    for (int kt = 0; kt <= ktmax; ++kt) {
        for (int i = tid; i < 16 * HD; i += 256) {
            int c = i / HD, d = i % HD;
            int t = kt * 16 + c;
            Ks[c][d] = (d < NOPE) ? KVU[(size_t)t * (NH * 256) + h * 256 + d]
                                  : KR[(size_t)t * ROPE + (d - NOPE)];
        }
        for (int i = tid; i < 16 * VDIM; i += 256) {
            int c = i / VDIM, d = i % VDIM;
            int t = kt * 16 + c;
            Vs[c][d] = KVU[(size_t)t * (NH * 256) + h * 256 + NOPE + d];
        }
        __syncthreads();

        // S = Q K^T  (each thread: row r, cols c0, c0+1)
        float s0 = 0.f, s1 = 0.f;
        const float* qp = &Qs[r][0];
        for (int k = 0; k < HD; k += 4) {
            float4 q4 = *(const float4*)(qp + k);
            float4 k0v = *(const float4*)(&Ks[c0 + 0][k]);
            float4 k1v = *(const float4*)(&Ks[c0 + 1][k]);
            s0 += q4.x * k0v.x + q4.y * k0v.y + q4.z * k0v.z + q4.w * k0v.w;
            s1 += q4.x * k1v.x + q4.y * k1v.y + q4.z * k1v.z + q4.w * k1v.w;
        }
        int qrow = qt * 32 + r;
        int kb = kt * 16 + c0;
        Sb[r][c0 + 0] = (kb + 0 <= qrow) ? s0 * SCALE : -1e30f;
        Sb[r][c0 + 1] = (kb + 1 <= qrow) ? s1 * SCALE : -1e30f;
        __syncthreads();

        if (tid < 32) {
            float mold = mrow[tid];
            float mt = mold;
            #pragma unroll
            for (int c = 0; c < 16; ++c) mt = fmaxf(mt, Sb[tid][c]);
            float al = __expf(mold - mt);
            float sum = 0.f;
            #pragma unroll
            for (int c = 0; c < 16; ++c) {
                float p = __expf(Sb[tid][c] - mt);
                Sb[tid][c] = p;
                sum += p;
            }
            lrow[tid] = lrow[tid] * al + sum;
            mrow[tid] = mt;
            arow[tid] = al;
        }
        __syncthreads();

        float al = arow[r];
        #pragma unroll
        for (int j = 0; j < 16; ++j) o[j] *= al;
        #pragma unroll
        for (int c = 0; c < 16; ++c) {
            float p = Sb[r][c];
            const float* vp = &Vs[c][d0];
            #pragma unroll
            for (int j = 0; j < 16; j += 4) {
                float4 v4 = *(const float4*)(vp + j);
                o[j + 0] += p * v4.x;
                o[j + 1] += p * v4.y;
                o[j + 2] += p * v4.z;
                o[j + 3] += p * v4.w;
            }
        }
        __syncthreads();
    }

    float inv = 1.0f / lrow[r];
    int t = qt * 32 + r;
    #pragma unroll
    for (int j = 0; j < 16; ++j)
        AO[(size_t)t * (NH * VDIM) + h * VDIM + d0 + j] = o[j] * inv;
}

// ---------------- launch ----------------
extern "C" void kernel_launch(void* const* d_in, const int* in_sizes, int n_in,
                              void* d_out, int out_size, void* d_ws, size_t ws_size,
                              hipStream_t stream) {
    const float* x        = (const float*)d_in[0];
    const float* freqs    = (const float*)d_in[1];
    // d_in[2] = mask (unused; causality applied analytically)
    const float* wq_down  = (const float*)d_in[3];
    const float* q_norm_w = (const float*)d_in[4];
    const float* wq_nope  = (const float*)d_in[5];
    const float* wq_rope  = (const float*)d_in[6];
    const float* wkv_down = (const float*)d_in[7];
    const float* kv_norm_w= (const float*)d_in[8];
    const float* wkv_up   = (const float*)d_in[9];
    const float* wo       = (const float*)d_in[10];
    float* out = (float*)d_out;

    float* ws = (float*)d_ws;
    // workspace layout (fp32 elements) — total 30,277,632 floats = 121.1 MB
    float* t1   = ws;                       // 3072*1536  (q_lat)
    float* kvd  = t1   + 4718592;           // 3072*576
    float* ckvn = kvd  + 1769472;           // 3072*512
    float* kr   = ckvn + 1572864;           // 3072*64
    float* qn   = kr   + 196608;            // 3072*2048
    float* qr   = qn   + 6291456;           // 3072*1024
    float* kvu  = qr   + 3145728;           // 3072*4096
    float* ao   = t1;                       // 3072*2048 (aliases dead t1+kvd: 6.29M <= 6.49M)

    gemm128<<<dim3(QLORA / 128, T_SEQ / 128), 256, 0, stream>>>(x, wq_down, t1, T_SEQ, QLORA, DIM);
    gemm128<<<dim3((KVLORA + ROPE + 127) / 128, T_SEQ / 128), 256, 0, stream>>>(x, wkv_down, kvd, T_SEQ, KVLORA + ROPE, DIM);

    rmsnorm_rows<<<T_SEQ, 256, 0, stream>>>(t1, q_norm_w, QLORA);
    kv_post<<<T_SEQ, 256, 0, stream>>>(kvd, kv_norm_w, freqs, ckvn, kr);

    gemm128<<<dim3(NH * NOPE / 128, T_SEQ / 128), 256, 0, stream>>>(t1, wq_nope, qn, T_SEQ, NH * NOPE, QLORA);
    gemm128<<<dim3(NH * ROPE / 128, T_SEQ / 128), 256, 0, stream>>>(t1, wq_rope, qr, T_SEQ, NH * ROPE, QLORA);
    rope_q<<<(T_SEQ * NH * 32 + 255) / 256, 256, 0, stream>>>(qr, freqs);

    gemm128<<<dim3(NH * 256 / 128, T_SEQ / 128), 256, 0, stream>>>(ckvn, wkv_up, kvu, T_SEQ, NH * 256, KVLORA);

    attn_kernel<<<dim3(T_SEQ / 32, NH), 256, 0, stream>>>(qn, qr, kvu, kr, ao);

    gemm128<<<dim3(DIM / 128, T_SEQ / 128), 256, 0, stream>>>(ao, wo, out, T_SEQ, DIM, DIM);
}

// Round 4
// 872.561 us; speedup vs baseline: 7.9698x; 7.9698x over previous
//
#include <hip/hip_runtime.h>
#include <hip/hip_bf16.h>

typedef __bf16 bf16_t;
typedef __bf16 bf16x8 __attribute__((ext_vector_type(8)));
typedef float f32x4 __attribute__((ext_vector_type(4)));

// Problem constants
#define T_SEQ 3072
#define DIM 2048
#define NH 16
#define QLORA 1536
#define KVLORA 512
#define NOPE 128
#define ROPE 64
#define VDIM 128
#define HD 192          // NOPE+ROPE
#define SCALE 0.07216878364870323f  // 192^-0.5

// ---------------- helpers ----------------
__device__ inline float wave_reduce_sum(float v) {
    #pragma unroll
    for (int off = 32; off > 0; off >>= 1) v += __shfl_down(v, off);
    return v;
}

__device__ inline float block_reduce_sum_256(float v) {
    __shared__ float red[4];
    int lane = threadIdx.x & 63, w = threadIdx.x >> 6;
    v = wave_reduce_sum(v);
    if (lane == 0) red[w] = v;
    __syncthreads();
    if (threadIdx.x == 0) red[0] = red[0] + red[1] + red[2] + red[3];
    __syncthreads();
    return red[0];
}

// ---------------- fp32 -> bf16 convert (n multiple of 4) ----------------
__global__ void f2b_kernel(const float* __restrict__ in, bf16_t* __restrict__ out, int n) {
    int i = (blockIdx.x * 256 + threadIdx.x) * 4;
    if (i < n) {
        float4 v = *(const float4*)&in[i];
        bf16_t o[4] = {(bf16_t)v.x, (bf16_t)v.y, (bf16_t)v.z, (bf16_t)v.w};
        *(uint2*)&out[i] = *(const uint2*)o;
    }
}

// ---------------- fp32 [K][N] -> bf16 [N][K] transpose-convert ----------------
// grid (N/32, K/32), block 256 (32x8). K,N multiples of 32 (all weights are).
__global__ __launch_bounds__(256) void transp_kernel(
    const float* __restrict__ in, bf16_t* __restrict__ out, int K, int N)
{
    __shared__ float tile[32][33];
    int k0 = blockIdx.y * 32, n0 = blockIdx.x * 32;
    int tx = threadIdx.x & 31, ty = threadIdx.x >> 5;
    #pragma unroll
    for (int i = 0; i < 4; ++i)
        tile[ty + i * 8][tx] = in[(size_t)(k0 + ty + i * 8) * N + n0 + tx];
    __syncthreads();
    #pragma unroll
    for (int i = 0; i < 4; ++i)
        out[(size_t)(n0 + ty + i * 8) * K + k0 + tx] = (bf16_t)tile[tx][ty + i * 8];
}

// ---------------- MFMA GEMM: C[M,N] = A[M,K](bf16) x Bt[N,K](bf16), fp32 acc ----------------
// 128x128 tile, BK=32, 256 threads (4 waves), each wave 4x4 grid of 16x16 MFMA tiles.
// LDS rows padded to 40 bf16 (80B): 2-way bank aliasing only (free).
__global__ __launch_bounds__(256) void gemm_mfma(
    const bf16_t* __restrict__ A, const bf16_t* __restrict__ Bt,
    float* __restrict__ Cf, bf16_t* __restrict__ Cb,
    int M, int N, int K, int writef)
{
    __shared__ __align__(16) bf16_t As[128 * 40];
    __shared__ __align__(16) bf16_t Bs[128 * 40];
    int tid = threadIdx.x;
    int w = tid >> 6, lane = tid & 63;
    int quad = lane >> 4, l16 = lane & 15;
    int bm = blockIdx.y * 128, bn = blockIdx.x * 128;
    int wm = (w & 1) * 64, wn = (w >> 1) * 64;

    f32x4 acc[4][4];
    #pragma unroll
    for (int i = 0; i < 4; ++i)
        #pragma unroll
        for (int j = 0; j < 4; ++j)
            acc[i][j] = (f32x4){0.f, 0.f, 0.f, 0.f};

    for (int k0 = 0; k0 < K; k0 += 32) {
        #pragma unroll
        for (int l = 0; l < 2; ++l) {
            int cid = tid + l * 256;            // 0..511
            int row = cid >> 2, ch = cid & 3;   // 4 16B-chunks per row of 32 bf16
            uint4 av = *(const uint4*)&A[(size_t)(bm + row) * K + k0 + ch * 8];
            *(uint4*)&As[row * 40 + ch * 8] = av;
            int brow = bn + row;
            uint4 bv = {0u, 0u, 0u, 0u};
            if (brow < N) bv = *(const uint4*)&Bt[(size_t)brow * K + k0 + ch * 8];
            *(uint4*)&Bs[row * 40 + ch * 8] = bv;
        }
        __syncthreads();
        bf16x8 af[4], bfr[4];
        #pragma unroll
        for (int t = 0; t < 4; ++t) {
            af[t]  = *(const bf16x8*)&As[(wm + t * 16 + l16) * 40 + quad * 8];
            bfr[t] = *(const bf16x8*)&Bs[(wn + t * 16 + l16) * 40 + quad * 8];
        }
        #pragma unroll
        for (int i = 0; i < 4; ++i)
            #pragma unroll
            for (int j = 0; j < 4; ++j)
                acc[i][j] = __builtin_amdgcn_mfma_f32_16x16x32_bf16(af[i], bfr[j], acc[i][j], 0, 0, 0);
        __syncthreads();
    }

    // C/D layout: col = lane&15, row = quad*4 + reg  (m89/m91-verified)
    #pragma unroll
    for (int i = 0; i < 4; ++i) {
        #pragma unroll
        for (int j = 0; j < 4; ++j) {
            #pragma unroll
            for (int r = 0; r < 4; ++r) {
                int row = bm + wm + i * 16 + quad * 4 + r;
                int col = bn + wn + j * 16 + l16;
                if (col < N) {
                    if (writef) Cf[(size_t)row * N + col] = acc[i][j][r];
                    else        Cb[(size_t)row * N + col] = (bf16_t)acc[i][j][r];
                }
            }
        }
    }
}

// ---------------- rmsnorm in-place over rows (bf16 storage, fp32 weights/math) ----------------
__global__ __launch_bounds__(256) void rmsnorm_rows(
    bf16_t* __restrict__ X, const float* __restrict__ w, int N)
{
    int row = blockIdx.x;
    bf16_t* x = X + (size_t)row * N;
    float ss = 0.f;
    for (int i = threadIdx.x; i < N; i += 256) { float v = (float)x[i]; ss += v * v; }
    ss = block_reduce_sum_256(ss);
    float sc = rsqrtf(ss / (float)N + 1e-6f);
    for (int i = threadIdx.x; i < N; i += 256)
        x[i] = (bf16_t)((float)x[i] * sc * w[i]);
}

// ---------------- kv post: rmsnorm(c_kv) -> ckvn ; rope(k_rope_raw) -> kr ----------------
__global__ __launch_bounds__(256) void kv_post(
    const bf16_t* __restrict__ kvd, const float* __restrict__ w,
    const float* __restrict__ freqs,
    bf16_t* __restrict__ ckvn, bf16_t* __restrict__ kr)
{
    int row = blockIdx.x;
    const bf16_t* src = kvd + (size_t)row * (KVLORA + ROPE);
    float ss = 0.f;
    for (int i = threadIdx.x; i < KVLORA; i += 256) { float v = (float)src[i]; ss += v * v; }
    ss = block_reduce_sum_256(ss);
    float sc = rsqrtf(ss / (float)KVLORA + 1e-6f);
    for (int i = threadIdx.x; i < KVLORA; i += 256)
        ckvn[(size_t)row * KVLORA + i] = (bf16_t)((float)src[i] * sc * w[i]);
    if (threadIdx.x < 32) {
        int i = threadIdx.x;
        float f = freqs[row * 32 + i];
        float c = cosf(f), s = sinf(f);
        float x1 = (float)src[KVLORA + 2 * i], x2 = (float)src[KVLORA + 2 * i + 1];
        kr[(size_t)row * ROPE + 2 * i]     = (bf16_t)(x1 * c - x2 * s);
        kr[(size_t)row * ROPE + 2 * i + 1] = (bf16_t)(x1 * s + x2 * c);
    }
}

// ---------------- rope on q_rope in-place: qr [T][NH*64] bf16 ----------------
__global__ void rope_q(bf16_t* __restrict__ qr, const float* __restrict__ freqs) {
    int idx = blockIdx.x * 256 + threadIdx.x;   // T*NH*32 pairs
    if (idx >= T_SEQ * NH * 32) return;
    int t = idx >> 9;
    int rem = idx & 511;
    int h = rem >> 5;
    int i = rem & 31;
    float f = freqs[t * 32 + i];
    float c = cosf(f), s = sinf(f);
    bf16_t* p = qr + (size_t)t * (NH * ROPE) + h * ROPE + 2 * i;
    float x1 = (float)p[0], x2 = (float)p[1];
    p[0] = (bf16_t)(x1 * c - x2 * s);
    p[1] = (bf16_t)(x1 * s + x2 * c);
}

// ---------------- MFMA flash attention (causal) ----------------
// grid (48 q-tiles of 64, 16 heads), block 256 (4 waves). Wave w owns q rows w*16..w*16+15.
// QK^T: 2 col-tiles x 6 k-steps MFMA; softmax stats in registers (16-lane shfl reductions);
// P -> A-layout via per-wave LDS round-trip; PV: V staged transposed.
#define QK_STRIDE 200   // 192+8 bf16 (400B rows: 2-way bank aliasing, 16B aligned)
#define V_STRIDE 40     // 32+8
#define P_STRIDE 40
__global__ __launch_bounds__(256) void attn_mfma(
    const bf16_t* __restrict__ QN, const bf16_t* __restrict__ QR,
    const bf16_t* __restrict__ KVU, const bf16_t* __restrict__ KR,
    bf16_t* __restrict__ AO)
{
    __shared__ __align__(16) bf16_t Qs[64 * QK_STRIDE];   // 25600 B
    __shared__ __align__(16) bf16_t Ks[32 * QK_STRIDE];   // 12800 B
    __shared__ __align__(16) bf16_t Vs[VDIM * V_STRIDE];  // 10240 B
    __shared__ __align__(16) bf16_t Ps[4 * 16 * P_STRIDE];//  5120 B  (53760 total -> 3 blk/CU)

    int tid = threadIdx.x;
    int w = tid >> 6, lane = tid & 63;
    int quad = lane >> 4, l16 = lane & 15;
    int qt = blockIdx.x, h = blockIdx.y;
    int qbase = qt * 64;

    // stage Q tile: 64 rows x 192 (nope 16 chunks + rope 8 chunks of 8 bf16)
    #pragma unroll
    for (int l = 0; l < 6; ++l) {
        int cid = tid + l * 256;          // 0..1535
        int row = cid / 24, ch = cid % 24;
        uint4 v;
        if (ch < 16) v = *(const uint4*)&QN[(size_t)(qbase + row) * (NH * NOPE) + h * NOPE + ch * 8];
        else         v = *(const uint4*)&QR[(size_t)(qbase + row) * (NH * ROPE) + h * ROPE + (ch - 16) * 8];
        *(uint4*)&Qs[row * QK_STRIDE + ch * 8] = v;
    }

    f32x4 o[8];
    #pragma unroll
    for (int nt = 0; nt < 8; ++nt) o[nt] = (f32x4){0.f, 0.f, 0.f, 0.f};
    float m_r[4] = {-1e30f, -1e30f, -1e30f, -1e30f};
    float l_r[4] = {0.f, 0.f, 0.f, 0.f};

    int ktiles = 2 * qt + 2;
    for (int kt = 0; kt < ktiles; ++kt) {
        int kbase = kt * 32;
        __syncthreads();
        // stage K: 32 rows x 192
        #pragma unroll
        for (int l = 0; l < 3; ++l) {
            int cid = tid + l * 256;      // 0..767
            int row = cid / 24, ch = cid % 24;
            uint4 v;
            if (ch < 16) v = *(const uint4*)&KVU[(size_t)(kbase + row) * (NH * 256) + h * 256 + ch * 8];
            else         v = *(const uint4*)&KR[(size_t)(kbase + row) * ROPE + (ch - 16) * 8];
            *(uint4*)&Ks[row * QK_STRIDE + ch * 8] = v;
        }
        // stage V transposed: Vs[d][k] ; 32 rows x 128 dims
        #pragma unroll
        for (int l = 0; l < 2; ++l) {
            int cid = tid + l * 256;      // 0..511
            int row = cid >> 4, ch = cid & 15;
            union { uint4 u; bf16_t e[8]; } cv;
            cv.u = *(const uint4*)&KVU[(size_t)(kbase + row) * (NH * 256) + h * 256 + NOPE + ch * 8];
            #pragma unroll
            for (int j = 0; j < 8; ++j)
                Vs[(ch * 8 + j) * V_STRIDE + row] = cv.e[j];
        }
        __syncthreads();

        // S = Q K^T : two 16-col tiles, 6 MFMA k-steps each
        f32x4 S0 = (f32x4){0.f, 0.f, 0.f, 0.f};
        f32x4 S1 = (f32x4){0.f, 0.f, 0.f, 0.f};
        #pragma unroll
        for (int kk = 0; kk < 6; ++kk) {
            bf16x8 qf = *(const bf16x8*)&Qs[(w * 16 + l16) * QK_STRIDE + kk * 32 + quad * 8];
            bf16x8 k0 = *(const bf16x8*)&Ks[(l16) * QK_STRIDE + kk * 32 + quad * 8];
            bf16x8 k1 = *(const bf16x8*)&Ks[(16 + l16) * QK_STRIDE + kk * 32 + quad * 8];
            S0 = __builtin_amdgcn_mfma_f32_16x16x32_bf16(qf, k0, S0, 0, 0, 0);
            S1 = __builtin_amdgcn_mfma_f32_16x16x32_bf16(qf, k1, S1, 0, 0, 0);
        }

        // online softmax: lane holds rows quad*4+j, col l16 (+16)
        float alpha_r[4];
        #pragma unroll
        for (int j = 0; j < 4; ++j) {
            int grow = qbase + w * 16 + quad * 4 + j;
            float s0 = (kbase + l16      <= grow) ? S0[j] * SCALE : -1e30f;
            float s1 = (kbase + 16 + l16 <= grow) ? S1[j] * SCALE : -1e30f;
            float mx = fmaxf(s0, s1);
            #pragma unroll
            for (int off = 1; off < 16; off <<= 1) mx = fmaxf(mx, __shfl_xor(mx, off));
            float mn = fmaxf(m_r[j], mx);
            float a  = __expf(m_r[j] - mn);
            float p0 = __expf(s0 - mn);
            float p1 = __expf(s1 - mn);
            float rs = p0 + p1;
            #pragma unroll
            for (int off = 1; off < 16; off <<= 1) rs += __shfl_xor(rs, off);
            l_r[j] = l_r[j] * a + rs;
            m_r[j] = mn;
            alpha_r[j] = a;
            Ps[w * 640 + (quad * 4 + j) * P_STRIDE + l16]      = (bf16_t)p0;
            Ps[w * 640 + (quad * 4 + j) * P_STRIDE + 16 + l16] = (bf16_t)p1;
        }

        // rescale O, then O += P V
        #pragma unroll
        for (int nt = 0; nt < 8; ++nt)
            #pragma unroll
            for (int j = 0; j < 4; ++j)
                o[nt][j] *= alpha_r[j];

        bf16x8 pf = *(const bf16x8*)&Ps[w * 640 + l16 * P_STRIDE + quad * 8];
        #pragma unroll
        for (int nt = 0; nt < 8; ++nt) {
            bf16x8 vf = *(const bf16x8*)&Vs[(nt * 16 + l16) * V_STRIDE + quad * 8];
            o[nt] = __builtin_amdgcn_mfma_f32_16x16x32_bf16(pf, vf, o[nt], 0, 0, 0);
        }
    }

    // write O (C-layout): row = quad*4+j, col = nt*16+l16
    float inv[4];
    #pragma unroll
    for (int j = 0; j < 4; ++j) inv[j] = 1.0f / l_r[j];
    #pragma unroll
    for (int nt = 0; nt < 8; ++nt) {
        #pragma unroll
        for (int j = 0; j < 4; ++j) {
            int row = qbase + w * 16 + quad * 4 + j;
            AO[(size_t)row * (NH * VDIM) + h * VDIM + nt * 16 + l16] = (bf16_t)(o[nt][j] * inv[j]);
        }
    }
}

// ---------------- launch ----------------
extern "C" void kernel_launch(void* const* d_in, const int* in_sizes, int n_in,
                              void* d_out, int out_size, void* d_ws, size_t ws_size,
                              hipStream_t stream) {
    const float* x        = (const float*)d_in[0];
    const float* freqs    = (const float*)d_in[1];
    // d_in[2] = mask (unused; causality applied analytically)
    const float* wq_down  = (const float*)d_in[3];
    const float* q_norm_w = (const float*)d_in[4];
    const float* wq_nope  = (const float*)d_in[5];
    const float* wq_rope  = (const float*)d_in[6];
    const float* wkv_down = (const float*)d_in[7];
    const float* kv_norm_w= (const float*)d_in[8];
    const float* wkv_up   = (const float*)d_in[9];
    const float* wo       = (const float*)d_in[10];
    float* out = (float*)d_out;

    bf16_t* ws = (bf16_t*)d_ws;
    // workspace (bf16 elems) — total 58,195,968 = 116.4 MB
    bf16_t* xb     = ws;                     // 3072*2048
    bf16_t* wqd_t  = xb     + 6291456;       // [1536][2048]
    bf16_t* wkvd_t = wqd_t  + 3145728;       // [576][2048]
    bf16_t* wqn_t  = wkvd_t + 1179648;       // [2048][1536]
    bf16_t* wqr_t  = wqn_t  + 3145728;       // [1024][1536]
    bf16_t* wkvu_t = wqr_t  + 1572864;       // [4096][512]
    bf16_t* wo_t   = wkvu_t + 2097152;       // [2048][2048]
    bf16_t* t1     = wo_t   + 4194304;       // 3072*1536 (q_lat)
    bf16_t* kvd    = t1     + 4718592;       // 3072*576
    bf16_t* ckvn   = kvd    + 1769472;       // 3072*512
    bf16_t* kr     = ckvn   + 1572864;       // 3072*64
    bf16_t* qn     = kr     + 196608;        // 3072*2048
    bf16_t* qr     = qn     + 6291456;       // 3072*1024
    bf16_t* kvu    = qr     + 3145728;       // 3072*4096
    bf16_t* ao     = kvu    + 12582912;      // 3072*2048

    // converts + weight transposes
    f2b_kernel<<<T_SEQ * DIM / 4 / 256, 256, 0, stream>>>(x, xb, T_SEQ * DIM);
    transp_kernel<<<dim3(QLORA / 32, DIM / 32), 256, 0, stream>>>(wq_down, wqd_t, DIM, QLORA);
    transp_kernel<<<dim3((KVLORA + ROPE) / 32, DIM / 32), 256, 0, stream>>>(wkv_down, wkvd_t, DIM, KVLORA + ROPE);
    transp_kernel<<<dim3(NH * NOPE / 32, QLORA / 32), 256, 0, stream>>>(wq_nope, wqn_t, QLORA, NH * NOPE);
    transp_kernel<<<dim3(NH * ROPE / 32, QLORA / 32), 256, 0, stream>>>(wq_rope, wqr_t, QLORA, NH * ROPE);
    transp_kernel<<<dim3(NH * 256 / 32, KVLORA / 32), 256, 0, stream>>>(wkv_up, wkvu_t, KVLORA, NH * 256);
    transp_kernel<<<dim3(DIM / 32, DIM / 32), 256, 0, stream>>>(wo, wo_t, DIM, DIM);

    // down-projections
    gemm_mfma<<<dim3(QLORA / 128, T_SEQ / 128), 256, 0, stream>>>(xb, wqd_t, nullptr, t1, T_SEQ, QLORA, DIM, 0);
    gemm_mfma<<<dim3(5, T_SEQ / 128), 256, 0, stream>>>(xb, wkvd_t, nullptr, kvd, T_SEQ, KVLORA + ROPE, DIM, 0);

    rmsnorm_rows<<<T_SEQ, 256, 0, stream>>>(t1, q_norm_w, QLORA);
    kv_post<<<T_SEQ, 256, 0, stream>>>(kvd, kv_norm_w, freqs, ckvn, kr);

    // up-projections
    gemm_mfma<<<dim3(NH * NOPE / 128, T_SEQ / 128), 256, 0, stream>>>(t1, wqn_t, nullptr, qn, T_SEQ, NH * NOPE, QLORA, 0);
    gemm_mfma<<<dim3(NH * ROPE / 128, T_SEQ / 128), 256, 0, stream>>>(t1, wqr_t, nullptr, qr, T_SEQ, NH * ROPE, QLORA, 0);
    rope_q<<<(T_SEQ * NH * 32 + 255) / 256, 256, 0, stream>>>(qr, freqs);
    gemm_mfma<<<dim3(NH * 256 / 128, T_SEQ / 128), 256, 0, stream>>>(ckvn, wkvu_t, nullptr, kvu, T_SEQ, NH * 256, KVLORA, 0);

    // attention
    attn_mfma<<<dim3(T_SEQ / 64, NH), 256, 0, stream>>>(qn, qr, kvu, kr, ao);

    // output projection (fp32 out)
    gemm_mfma<<<dim3(DIM / 128, T_SEQ / 128), 256, 0, stream>>>(ao, wo_t, out, nullptr, T_SEQ, DIM, DIM, 1);
}

// Round 5
// 825.611 us; speedup vs baseline: 8.4230x; 1.0569x over previous
//
#include <hip/hip_runtime.h>
#include <hip/hip_bf16.h>

typedef __bf16 bf16_t;
typedef __bf16 bf16x8 __attribute__((ext_vector_type(8)));
typedef float f32x4 __attribute__((ext_vector_type(4)));

// Problem constants
#define T_SEQ 3072
#define DIM 2048
#define NH 16
#define QLORA 1536
#define KVLORA 512
#define NOPE 128
#define ROPE 64
#define VDIM 128
#define HD 192          // NOPE+ROPE
#define SCALE 0.07216878364870323f  // 192^-0.5

// ---------------- helpers ----------------
__device__ inline float wave_reduce_sum(float v) {
    #pragma unroll
    for (int off = 32; off > 0; off >>= 1) v += __shfl_down(v, off);
    return v;
}

__device__ inline float block_reduce_sum_256(float v) {
    __shared__ float red[4];
    int lane = threadIdx.x & 63, w = threadIdx.x >> 6;
    v = wave_reduce_sum(v);
    if (lane == 0) red[w] = v;
    __syncthreads();
    if (threadIdx.x == 0) red[0] = red[0] + red[1] + red[2] + red[3];
    __syncthreads();
    return red[0];
}

// ---------------- fp32 -> bf16 convert (n multiple of 4) ----------------
__global__ void f2b_kernel(const float* __restrict__ in, bf16_t* __restrict__ out, int n) {
    int i = (blockIdx.x * 256 + threadIdx.x) * 4;
    if (i < n) {
        float4 v = *(const float4*)&in[i];
        bf16_t o[4] = {(bf16_t)v.x, (bf16_t)v.y, (bf16_t)v.z, (bf16_t)v.w};
        *(uint2*)&out[i] = *(const uint2*)o;
    }
}

// ---------------- fp32 [K][N] -> bf16 [N][K] transpose-convert ----------------
__global__ __launch_bounds__(256) void transp_kernel(
    const float* __restrict__ in, bf16_t* __restrict__ out, int K, int N)
{
    __shared__ float tile[32][33];
    int k0 = blockIdx.y * 32, n0 = blockIdx.x * 32;
    int tx = threadIdx.x & 31, ty = threadIdx.x >> 5;
    #pragma unroll
    for (int i = 0; i < 4; ++i)
        tile[ty + i * 8][tx] = in[(size_t)(k0 + ty + i * 8) * N + n0 + tx];
    __syncthreads();
    #pragma unroll
    for (int i = 0; i < 4; ++i)
        out[(size_t)(n0 + ty + i * 8) * K + k0 + tx] = (bf16_t)tile[tx][ty + i * 8];
}

// ---------------- bf16 kvu V-part -> vt[h][d][t] transpose ----------------
// grid (96, 4, 16), block 256.
__global__ __launch_bounds__(256) void vt_transp(
    const bf16_t* __restrict__ kvu, bf16_t* __restrict__ vt)
{
    __shared__ bf16_t tile[32][34];
    int t0 = blockIdx.x * 32, d0 = blockIdx.y * 32, h = blockIdx.z;
    int tx = threadIdx.x & 31, ty = threadIdx.x >> 5;
    #pragma unroll
    for (int i = 0; i < 4; ++i)
        tile[ty + i * 8][tx] = kvu[(size_t)(t0 + ty + i * 8) * (NH * 256) + h * 256 + NOPE + d0 + tx];
    __syncthreads();
    #pragma unroll
    for (int i = 0; i < 4; ++i)
        vt[((size_t)h * VDIM + d0 + ty + i * 8) * T_SEQ + t0 + tx] = tile[tx][ty + i * 8];
}

// ---------------- MFMA GEMM: C[M,N] = A[M,K](bf16) x Bt[N,K](bf16), fp32 acc ----------------
__global__ __launch_bounds__(256) void gemm_mfma(
    const bf16_t* __restrict__ A, const bf16_t* __restrict__ Bt,
    float* __restrict__ Cf, bf16_t* __restrict__ Cb,
    int M, int N, int K, int writef)
{
    __shared__ __align__(16) bf16_t As[128 * 40];
    __shared__ __align__(16) bf16_t Bs[128 * 40];
    int tid = threadIdx.x;
    int w = tid >> 6, lane = tid & 63;
    int quad = lane >> 4, l16 = lane & 15;
    int bm = blockIdx.y * 128, bn = blockIdx.x * 128;
    int wm = (w & 1) * 64, wn = (w >> 1) * 64;

    f32x4 acc[4][4];
    #pragma unroll
    for (int i = 0; i < 4; ++i)
        #pragma unroll
        for (int j = 0; j < 4; ++j)
            acc[i][j] = (f32x4){0.f, 0.f, 0.f, 0.f};

    for (int k0 = 0; k0 < K; k0 += 32) {
        #pragma unroll
        for (int l = 0; l < 2; ++l) {
            int cid = tid + l * 256;
            int row = cid >> 2, ch = cid & 3;
            uint4 av = *(const uint4*)&A[(size_t)(bm + row) * K + k0 + ch * 8];
            *(uint4*)&As[row * 40 + ch * 8] = av;
            int brow = bn + row;
            uint4 bv = {0u, 0u, 0u, 0u};
            if (brow < N) bv = *(const uint4*)&Bt[(size_t)brow * K + k0 + ch * 8];
            *(uint4*)&Bs[row * 40 + ch * 8] = bv;
        }
        __syncthreads();
        bf16x8 af[4], bfr[4];
        #pragma unroll
        for (int t = 0; t < 4; ++t) {
            af[t]  = *(const bf16x8*)&As[(wm + t * 16 + l16) * 40 + quad * 8];
            bfr[t] = *(const bf16x8*)&Bs[(wn + t * 16 + l16) * 40 + quad * 8];
        }
        #pragma unroll
        for (int i = 0; i < 4; ++i)
            #pragma unroll
            for (int j = 0; j < 4; ++j)
                acc[i][j] = __builtin_amdgcn_mfma_f32_16x16x32_bf16(af[i], bfr[j], acc[i][j], 0, 0, 0);
        __syncthreads();
    }

    #pragma unroll
    for (int i = 0; i < 4; ++i) {
        #pragma unroll
        for (int j = 0; j < 4; ++j) {
            #pragma unroll
            for (int r = 0; r < 4; ++r) {
                int row = bm + wm + i * 16 + quad * 4 + r;
                int col = bn + wn + j * 16 + l16;
                if (col < N) {
                    if (writef) Cf[(size_t)row * N + col] = acc[i][j][r];
                    else        Cb[(size_t)row * N + col] = (bf16_t)acc[i][j][r];
                }
            }
        }
    }
}

// ---------------- rmsnorm in-place over rows ----------------
__global__ __launch_bounds__(256) void rmsnorm_rows(
    bf16_t* __restrict__ X, const float* __restrict__ w, int N)
{
    int row = blockIdx.x;
    bf16_t* x = X + (size_t)row * N;
    float ss = 0.f;
    for (int i = threadIdx.x; i < N; i += 256) { float v = (float)x[i]; ss += v * v; }
    ss = block_reduce_sum_256(ss);
    float sc = rsqrtf(ss / (float)N + 1e-6f);
    for (int i = threadIdx.x; i < N; i += 256)
        x[i] = (bf16_t)((float)x[i] * sc * w[i]);
}

// ---------------- kv post ----------------
__global__ __launch_bounds__(256) void kv_post(
    const bf16_t* __restrict__ kvd, const float* __restrict__ w,
    const float* __restrict__ freqs,
    bf16_t* __restrict__ ckvn, bf16_t* __restrict__ kr)
{
    int row = blockIdx.x;
    const bf16_t* src = kvd + (size_t)row * (KVLORA + ROPE);
    float ss = 0.f;
    for (int i = threadIdx.x; i < KVLORA; i += 256) { float v = (float)src[i]; ss += v * v; }
    ss = block_reduce_sum_256(ss);
    float sc = rsqrtf(ss / (float)KVLORA + 1e-6f);
    for (int i = threadIdx.x; i < KVLORA; i += 256)
        ckvn[(size_t)row * KVLORA + i] = (bf16_t)((float)src[i] * sc * w[i]);
    if (threadIdx.x < 32) {
        int i = threadIdx.x;
        float f = freqs[row * 32 + i];
        float c = cosf(f), s = sinf(f);
        float x1 = (float)src[KVLORA + 2 * i], x2 = (float)src[KVLORA + 2 * i + 1];
        kr[(size_t)row * ROPE + 2 * i]     = (bf16_t)(x1 * c - x2 * s);
        kr[(size_t)row * ROPE + 2 * i + 1] = (bf16_t)(x1 * s + x2 * c);
    }
}

// ---------------- rope on q_rope in-place ----------------
__global__ void rope_q(bf16_t* __restrict__ qr, const float* __restrict__ freqs) {
    int idx = blockIdx.x * 256 + threadIdx.x;
    if (idx >= T_SEQ * NH * 32) return;
    int t = idx >> 9;
    int rem = idx & 511;
    int h = rem >> 5;
    int i = rem & 31;
    float f = freqs[t * 32 + i];
    float c = cosf(f), s = sinf(f);
    bf16_t* p = qr + (size_t)t * (NH * ROPE) + h * ROPE + 2 * i;
    float x1 = (float)p[0], x2 = (float)p[1];
    p[0] = (bf16_t)(x1 * c - x2 * s);
    p[1] = (bf16_t)(x1 * s + x2 * c);
}

// ---------------- MFMA flash attention v3 (causal, fixed-max softmax) ----------------
// grid (48, 16), block 256 (4 waves). 64 q-rows per block (wave w: rows w*16..+15).
// KT=64. Q frags in registers; K LDS-staged (shared); V frags direct from global vt[h][d][t].
// l via ones-MFMA (no shuffles, no rescale). LDS 34.8KB -> 4 blocks/CU.
#define KS_STRIDE 200   // 192+8 bf16
#define P_STRIDE 72     // 64+8 bf16
__global__ __launch_bounds__(256) void attn_v3(
    const bf16_t* __restrict__ QN, const bf16_t* __restrict__ QR,
    const bf16_t* __restrict__ KVU, const bf16_t* __restrict__ KR,
    const bf16_t* __restrict__ Vt, bf16_t* __restrict__ AO)
{
    __shared__ __align__(16) bf16_t Ks[64 * KS_STRIDE];   // 25600 B
    __shared__ __align__(16) bf16_t Ps[4][16 * P_STRIDE]; //  9216 B

    int tid = threadIdx.x;
    int w = tid >> 6, lane = tid & 63;
    int quad = lane >> 4, l16 = lane & 15;
    int qx = blockIdx.x, h = blockIdx.y;
    int qt = (qx % 3) * 16 + qx / 3;     // CU-triple load-balance remap
    int qbase = qt * 64;

    // Q fragments (A-operand rows = l16) straight from global into registers
    bf16x8 qf[6];
    {
        int qrow = qbase + w * 16 + l16;
        #pragma unroll
        for (int kk = 0; kk < 4; ++kk)
            qf[kk] = *(const bf16x8*)&QN[(size_t)qrow * (NH * NOPE) + h * NOPE + kk * 32 + quad * 8];
        #pragma unroll
        for (int kk = 4; kk < 6; ++kk)
            qf[kk] = *(const bf16x8*)&QR[(size_t)qrow * (NH * ROPE) + h * ROPE + (kk - 4) * 32 + quad * 8];
    }

    bf16x8 ones;
    #pragma unroll
    for (int i = 0; i < 8; ++i) ones[i] = (bf16_t)1.0f;

    f32x4 o[8];
    #pragma unroll
    for (int nt = 0; nt < 8; ++nt) o[nt] = (f32x4){0.f, 0.f, 0.f, 0.f};
    f32x4 lacc = (f32x4){0.f, 0.f, 0.f, 0.f};

    for (int kt = 0; kt <= qt; ++kt) {
        int kbase = kt * 64;
        // stage K: 64 rows x 192 bf16 (nope from KVU, rope from KR)
        #pragma unroll
        for (int l = 0; l < 6; ++l) {
            int cid = tid + l * 256;          // 0..1535
            int row = cid / 24, ch = cid % 24;
            uint4 v;
            if (ch < 16) v = *(const uint4*)&KVU[(size_t)(kbase + row) * (NH * 256) + h * 256 + ch * 8];
            else         v = *(const uint4*)&KR[(size_t)(kbase + row) * ROPE + (ch - 16) * 8];
            *(uint4*)&Ks[row * KS_STRIDE + ch * 8] = v;
        }
        __syncthreads();

        // S = Q K^T : 4 col-tiles x 6 k-steps
        f32x4 S[4];
        #pragma unroll
        for (int c = 0; c < 4; ++c) S[c] = (f32x4){0.f, 0.f, 0.f, 0.f};
        #pragma unroll
        for (int kk = 0; kk < 6; ++kk) {
            #pragma unroll
            for (int c = 0; c < 4; ++c) {
                bf16x8 kf = *(const bf16x8*)&Ks[(c * 16 + l16) * KS_STRIDE + kk * 32 + quad * 8];
                S[c] = __builtin_amdgcn_mfma_f32_16x16x32_bf16(qf[kk], kf, S[c], 0, 0, 0);
            }
        }

        // fixed-max softmax: p = exp(s*SCALE) (scores bounded ~|8|; softmax shift-invariant)
        #pragma unroll
        for (int c = 0; c < 4; ++c) {
            #pragma unroll
            for (int j = 0; j < 4; ++j) {
                int col = kbase + c * 16 + l16;
                int grow = qbase + w * 16 + quad * 4 + j;
                float p = (col <= grow) ? __expf(S[c][j] * SCALE) : 0.f;
                Ps[w][(quad * 4 + j) * P_STRIDE + c * 16 + l16] = (bf16_t)p;
            }
        }
        // wave-internal LDS write->read ordering (per-wave buffer, lockstep wave64)
        __asm__ volatile("s_waitcnt lgkmcnt(0)" ::: "memory");

        bf16x8 pf0 = *(const bf16x8*)&Ps[w][l16 * P_STRIDE + quad * 8];
        bf16x8 pf1 = *(const bf16x8*)&Ps[w][l16 * P_STRIDE + 32 + quad * 8];
        // l += rowsum(P) via ones-MFMA (all cols of lacc identical)
        lacc = __builtin_amdgcn_mfma_f32_16x16x32_bf16(pf0, ones, lacc, 0, 0, 0);
        lacc = __builtin_amdgcn_mfma_f32_16x16x32_bf16(pf1, ones, lacc, 0, 0, 0);

        // O += P V : V fragments direct from global vt[h][d][t]
        #pragma unroll
        for (int kk2 = 0; kk2 < 2; ++kk2) {
            bf16x8 pf = kk2 ? pf1 : pf0;
            #pragma unroll
            for (int nt = 0; nt < 8; ++nt) {
                bf16x8 vf = *(const bf16x8*)&Vt[((size_t)h * VDIM + nt * 16 + l16) * T_SEQ + kbase + kk2 * 32 + quad * 8];
                o[nt] = __builtin_amdgcn_mfma_f32_16x16x32_bf16(pf, vf, o[nt], 0, 0, 0);
            }
        }
        __syncthreads();   // protect Ks before restage
    }

    float inv[4];
    #pragma unroll
    for (int j = 0; j < 4; ++j) inv[j] = 1.0f / lacc[j];
    #pragma unroll
    for (int nt = 0; nt < 8; ++nt) {
        #pragma unroll
        for (int j = 0; j < 4; ++j) {
            int row = qbase + w * 16 + quad * 4 + j;
            AO[(size_t)row * (NH * VDIM) + h * VDIM + nt * 16 + l16] = (bf16_t)(o[nt][j] * inv[j]);
        }
    }
}

// ---------------- launch ----------------
extern "C" void kernel_launch(void* const* d_in, const int* in_sizes, int n_in,
                              void* d_out, int out_size, void* d_ws, size_t ws_size,
                              hipStream_t stream) {
    const float* x        = (const float*)d_in[0];
    const float* freqs    = (const float*)d_in[1];
    // d_in[2] = mask (unused; causality applied analytically)
    const float* wq_down  = (const float*)d_in[3];
    const float* q_norm_w = (const float*)d_in[4];
    const float* wq_nope  = (const float*)d_in[5];
    const float* wq_rope  = (const float*)d_in[6];
    const float* wkv_down = (const float*)d_in[7];
    const float* kv_norm_w= (const float*)d_in[8];
    const float* wkv_up   = (const float*)d_in[9];
    const float* wo       = (const float*)d_in[10];
    float* out = (float*)d_out;

    bf16_t* ws = (bf16_t*)d_ws;
    // workspace (bf16 elems) — total 58,195,968 = 116.4 MB
    bf16_t* xb     = ws;                     // 3072*2048
    bf16_t* wqd_t  = xb     + 6291456;       // [1536][2048]
    bf16_t* wkvd_t = wqd_t  + 3145728;       // [576][2048]
    bf16_t* wqn_t  = wkvd_t + 1179648;       // [2048][1536]
    bf16_t* wqr_t  = wqn_t  + 3145728;       // [1024][1536]
    bf16_t* wkvu_t = wqr_t  + 1572864;       // [4096][512]
    bf16_t* wo_t   = wkvu_t + 2097152;       // [2048][2048]
    bf16_t* t1     = wo_t   + 4194304;       // 3072*1536 (q_lat)
    bf16_t* kvd    = t1     + 4718592;       // 3072*576
    bf16_t* ckvn   = kvd    + 1769472;       // 3072*512
    bf16_t* kr     = ckvn   + 1572864;       // 3072*64
    bf16_t* qn     = kr     + 196608;        // 3072*2048
    bf16_t* qr     = qn     + 6291456;       // 3072*1024
    bf16_t* kvu    = qr     + 3145728;       // 3072*4096
    bf16_t* vt     = kvu    + 12582912;      // [16][128][3072]
    bf16_t* ao     = t1;                     // 3072*2048 (aliases dead t1+kvd)

    // converts + weight transposes
    f2b_kernel<<<T_SEQ * DIM / 4 / 256, 256, 0, stream>>>(x, xb, T_SEQ * DIM);
    transp_kernel<<<dim3(QLORA / 32, DIM / 32), 256, 0, stream>>>(wq_down, wqd_t, DIM, QLORA);
    transp_kernel<<<dim3((KVLORA + ROPE) / 32, DIM / 32), 256, 0, stream>>>(wkv_down, wkvd_t, DIM, KVLORA + ROPE);
    transp_kernel<<<dim3(NH * NOPE / 32, QLORA / 32), 256, 0, stream>>>(wq_nope, wqn_t, QLORA, NH * NOPE);
    transp_kernel<<<dim3(NH * ROPE / 32, QLORA / 32), 256, 0, stream>>>(wq_rope, wqr_t, QLORA, NH * ROPE);
    transp_kernel<<<dim3(NH * 256 / 32, KVLORA / 32), 256, 0, stream>>>(wkv_up, wkvu_t, KVLORA, NH * 256);
    transp_kernel<<<dim3(DIM / 32, DIM / 32), 256, 0, stream>>>(wo, wo_t, DIM, DIM);

    // down-projections
    gemm_mfma<<<dim3(QLORA / 128, T_SEQ / 128), 256, 0, stream>>>(xb, wqd_t, nullptr, t1, T_SEQ, QLORA, DIM, 0);
    gemm_mfma<<<dim3(5, T_SEQ / 128), 256, 0, stream>>>(xb, wkvd_t, nullptr, kvd, T_SEQ, KVLORA + ROPE, DIM, 0);

    rmsnorm_rows<<<T_SEQ, 256, 0, stream>>>(t1, q_norm_w, QLORA);
    kv_post<<<T_SEQ, 256, 0, stream>>>(kvd, kv_norm_w, freqs, ckvn, kr);

    // up-projections
    gemm_mfma<<<dim3(NH * NOPE / 128, T_SEQ / 128), 256, 0, stream>>>(t1, wqn_t, nullptr, qn, T_SEQ, NH * NOPE, QLORA, 0);
    gemm_mfma<<<dim3(NH * ROPE / 128, T_SEQ / 128), 256, 0, stream>>>(t1, wqr_t, nullptr, qr, T_SEQ, NH * ROPE, QLORA, 0);
    rope_q<<<(T_SEQ * NH * 32 + 255) / 256, 256, 0, stream>>>(qr, freqs);
    gemm_mfma<<<dim3(NH * 256 / 128, T_SEQ / 128), 256, 0, stream>>>(ckvn, wkvu_t, nullptr, kvu, T_SEQ, NH * 256, KVLORA, 0);

    // V transpose for attention B-operand
    vt_transp<<<dim3(T_SEQ / 32, VDIM / 32, NH), 256, 0, stream>>>(kvu, vt);

    // attention
    attn_v3<<<dim3(T_SEQ / 64, NH), 256, 0, stream>>>(qn, qr, kvu, kr, vt, ao);

    // output projection (fp32 out)
    gemm_mfma<<<dim3(DIM / 128, T_SEQ / 128), 256, 0, stream>>>(ao, wo_t, out, nullptr, T_SEQ, DIM, DIM, 1);
}

// Round 6
// 780.700 us; speedup vs baseline: 8.9075x; 1.0575x over previous
//
#include <hip/hip_runtime.h>
#include <hip/hip_bf16.h>

typedef __bf16 bf16_t;
typedef __bf16 bf16x8 __attribute__((ext_vector_type(8)));
typedef float f32x4 __attribute__((ext_vector_type(4)));

// Problem constants
#define T_SEQ 3072
#define DIM 2048
#define NH 16
#define QLORA 1536
#define KVLORA 512
#define NOPE 128
#define ROPE 64
#define VDIM 128
#define HD 192          // NOPE+ROPE
#define SCALE 0.07216878364870323f  // 192^-0.5
#define CHUNK 12        // k-tiles (of 64 keys) per attention block

// ---------------- helpers ----------------
__device__ inline float wave_reduce_sum(float v) {
    #pragma unroll
    for (int off = 32; off > 0; off >>= 1) v += __shfl_down(v, off);
    return v;
}

__device__ inline float block_reduce_sum_256(float v) {
    __shared__ float red[4];
    int lane = threadIdx.x & 63, w = threadIdx.x >> 6;
    v = wave_reduce_sum(v);
    if (lane == 0) red[w] = v;
    __syncthreads();
    if (threadIdx.x == 0) red[0] = red[0] + red[1] + red[2] + red[3];
    __syncthreads();
    return red[0];
}

// ---------------- fp32 -> bf16 convert ----------------
__global__ void f2b_kernel(const float* __restrict__ in, bf16_t* __restrict__ out, int n) {
    int i = (blockIdx.x * 256 + threadIdx.x) * 4;
    if (i < n) {
        float4 v = *(const float4*)&in[i];
        bf16_t o[4] = {(bf16_t)v.x, (bf16_t)v.y, (bf16_t)v.z, (bf16_t)v.w};
        *(uint2*)&out[i] = *(const uint2*)o;
    }
}

// ---------------- fp32 [K][N] -> bf16 [N][K] transpose-convert ----------------
__global__ __launch_bounds__(256) void transp_kernel(
    const float* __restrict__ in, bf16_t* __restrict__ out, int K, int N)
{
    __shared__ float tile[32][33];
    int k0 = blockIdx.y * 32, n0 = blockIdx.x * 32;
    int tx = threadIdx.x & 31, ty = threadIdx.x >> 5;
    #pragma unroll
    for (int i = 0; i < 4; ++i)
        tile[ty + i * 8][tx] = in[(size_t)(k0 + ty + i * 8) * N + n0 + tx];
    __syncthreads();
    #pragma unroll
    for (int i = 0; i < 4; ++i)
        out[(size_t)(n0 + ty + i * 8) * K + k0 + tx] = (bf16_t)tile[tx][ty + i * 8];
}

// ---------------- bf16 kvu V-part -> vt[h][d][t] transpose ----------------
__global__ __launch_bounds__(256) void vt_transp(
    const bf16_t* __restrict__ kvu, bf16_t* __restrict__ vt)
{
    __shared__ bf16_t tile[32][34];
    int t0 = blockIdx.x * 32, d0 = blockIdx.y * 32, h = blockIdx.z;
    int tx = threadIdx.x & 31, ty = threadIdx.x >> 5;
    #pragma unroll
    for (int i = 0; i < 4; ++i)
        tile[ty + i * 8][tx] = kvu[(size_t)(t0 + ty + i * 8) * (NH * 256) + h * 256 + NOPE + d0 + tx];
    __syncthreads();
    #pragma unroll
    for (int i = 0; i < 4; ++i)
        vt[((size_t)h * VDIM + d0 + ty + i * 8) * T_SEQ + t0 + tx] = tile[tx][ty + i * 8];
}

// ---------------- MFMA GEMM: C[M,N] = A[M,K](bf16) x Bt[N,K](bf16), fp32 acc ----------------
__global__ __launch_bounds__(256) void gemm_mfma(
    const bf16_t* __restrict__ A, const bf16_t* __restrict__ Bt,
    float* __restrict__ Cf, bf16_t* __restrict__ Cb,
    int M, int N, int K, int writef)
{
    __shared__ __align__(16) bf16_t As[128 * 40];
    __shared__ __align__(16) bf16_t Bs[128 * 40];
    int tid = threadIdx.x;
    int w = tid >> 6, lane = tid & 63;
    int quad = lane >> 4, l16 = lane & 15;
    int bm = blockIdx.y * 128, bn = blockIdx.x * 128;
    int wm = (w & 1) * 64, wn = (w >> 1) * 64;

    f32x4 acc[4][4];
    #pragma unroll
    for (int i = 0; i < 4; ++i)
        #pragma unroll
        for (int j = 0; j < 4; ++j)
            acc[i][j] = (f32x4){0.f, 0.f, 0.f, 0.f};

    for (int k0 = 0; k0 < K; k0 += 32) {
        #pragma unroll
        for (int l = 0; l < 2; ++l) {
            int cid = tid + l * 256;
            int row = cid >> 2, ch = cid & 3;
            uint4 av = *(const uint4*)&A[(size_t)(bm + row) * K + k0 + ch * 8];
            *(uint4*)&As[row * 40 + ch * 8] = av;
            int brow = bn + row;
            uint4 bv = {0u, 0u, 0u, 0u};
            if (brow < N) bv = *(const uint4*)&Bt[(size_t)brow * K + k0 + ch * 8];
            *(uint4*)&Bs[row * 40 + ch * 8] = bv;
        }
        __syncthreads();
        bf16x8 af[4], bfr[4];
        #pragma unroll
        for (int t = 0; t < 4; ++t) {
            af[t]  = *(const bf16x8*)&As[(wm + t * 16 + l16) * 40 + quad * 8];
            bfr[t] = *(const bf16x8*)&Bs[(wn + t * 16 + l16) * 40 + quad * 8];
        }
        #pragma unroll
        for (int i = 0; i < 4; ++i)
            #pragma unroll
            for (int j = 0; j < 4; ++j)
                acc[i][j] = __builtin_amdgcn_mfma_f32_16x16x32_bf16(af[i], bfr[j], acc[i][j], 0, 0, 0);
        __syncthreads();
    }

    #pragma unroll
    for (int i = 0; i < 4; ++i) {
        #pragma unroll
        for (int j = 0; j < 4; ++j) {
            #pragma unroll
            for (int r = 0; r < 4; ++r) {
                int row = bm + wm + i * 16 + quad * 4 + r;
                int col = bn + wn + j * 16 + l16;
                if (col < N) {
                    if (writef) Cf[(size_t)row * N + col] = acc[i][j][r];
                    else        Cb[(size_t)row * N + col] = (bf16_t)acc[i][j][r];
                }
            }
        }
    }
}

// ---------------- rmsnorm in-place over rows ----------------
__global__ __launch_bounds__(256) void rmsnorm_rows(
    bf16_t* __restrict__ X, const float* __restrict__ w, int N)
{
    int row = blockIdx.x;
    bf16_t* x = X + (size_t)row * N;
    float ss = 0.f;
    for (int i = threadIdx.x; i < N; i += 256) { float v = (float)x[i]; ss += v * v; }
    ss = block_reduce_sum_256(ss);
    float sc = rsqrtf(ss / (float)N + 1e-6f);
    for (int i = threadIdx.x; i < N; i += 256)
        x[i] = (bf16_t)((float)x[i] * sc * w[i]);
}

// ---------------- kv post ----------------
__global__ __launch_bounds__(256) void kv_post(
    const bf16_t* __restrict__ kvd, const float* __restrict__ w,
    const float* __restrict__ freqs,
    bf16_t* __restrict__ ckvn, bf16_t* __restrict__ kr)
{
    int row = blockIdx.x;
    const bf16_t* src = kvd + (size_t)row * (KVLORA + ROPE);
    float ss = 0.f;
    for (int i = threadIdx.x; i < KVLORA; i += 256) { float v = (float)src[i]; ss += v * v; }
    ss = block_reduce_sum_256(ss);
    float sc = rsqrtf(ss / (float)KVLORA + 1e-6f);
    for (int i = threadIdx.x; i < KVLORA; i += 256)
        ckvn[(size_t)row * KVLORA + i] = (bf16_t)((float)src[i] * sc * w[i]);
    if (threadIdx.x < 32) {
        int i = threadIdx.x;
        float f = freqs[row * 32 + i];
        float c = cosf(f), s = sinf(f);
        float x1 = (float)src[KVLORA + 2 * i], x2 = (float)src[KVLORA + 2 * i + 1];
        kr[(size_t)row * ROPE + 2 * i]     = (bf16_t)(x1 * c - x2 * s);
        kr[(size_t)row * ROPE + 2 * i + 1] = (bf16_t)(x1 * s + x2 * c);
    }
}

// ---------------- rope on q_rope in-place ----------------
__global__ void rope_q(bf16_t* __restrict__ qr, const float* __restrict__ freqs) {
    int idx = blockIdx.x * 256 + threadIdx.x;
    if (idx >= T_SEQ * NH * 32) return;
    int t = idx >> 9;
    int rem = idx & 511;
    int h = rem >> 5;
    int i = rem & 31;
    float f = freqs[t * 32 + i];
    float c = cosf(f), s = sinf(f);
    bf16_t* p = qr + (size_t)t * (NH * ROPE) + h * ROPE + 2 * i;
    float x1 = (float)p[0], x2 = (float)p[1];
    p[0] = (bf16_t)(x1 * c - x2 * s);
    p[1] = (bf16_t)(x1 * s + x2 * c);
}

// ---------------- split-K MFMA flash attention (causal, fixed-max softmax) ----------------
// grid (48 qt, 4 chunk, 16 h), block 256 (4 waves). Chunk cx covers k-tiles
// [cx*CHUNK, min(qt+1,(cx+1)*CHUNK)). Fixed-max softmax makes partials additive:
// each block writes raw O-sums (bf16) + l-sums (fp32) to its slot; combine kernel
// normalizes. 1920 active blocks, each <=12 iterations -> balanced occupancy.
#define KS_STRIDE 200   // 192+8 bf16
#define P_STRIDE 72     // 64+8 bf16
__device__ inline int slot_base(int qt, int h) {
    int b = qt / CHUNK;
    return h * 120 + qt + 6 * b * (b - 1) + (qt - CHUNK * b) * b;
}
__global__ __launch_bounds__(256) void attn_v4(
    const bf16_t* __restrict__ QN, const bf16_t* __restrict__ QR,
    const bf16_t* __restrict__ KVU, const bf16_t* __restrict__ KR,
    const bf16_t* __restrict__ Vt,
    bf16_t* __restrict__ Opart, float* __restrict__ lpart)
{
    __shared__ __align__(16) bf16_t Ks[64 * KS_STRIDE];   // 25600 B
    __shared__ __align__(16) bf16_t Ps[4][16 * P_STRIDE]; //  9216 B

    int qt = blockIdx.x, cx = blockIdx.y, h = blockIdx.z;
    if (cx > qt / CHUNK) return;
    int slot = slot_base(qt, h) + cx;
    int kt0 = cx * CHUNK;
    int kt1 = min(qt + 1, kt0 + CHUNK);

    int tid = threadIdx.x;
    int w = tid >> 6, lane = tid & 63;
    int quad = lane >> 4, l16 = lane & 15;
    int qbase = qt * 64;

    // Q fragments (A-operand rows = l16) straight from global into registers
    bf16x8 qf[6];
    {
        int qrow = qbase + w * 16 + l16;
        #pragma unroll
        for (int kk = 0; kk < 4; ++kk)
            qf[kk] = *(const bf16x8*)&QN[(size_t)qrow * (NH * NOPE) + h * NOPE + kk * 32 + quad * 8];
        #pragma unroll
        for (int kk = 4; kk < 6; ++kk)
            qf[kk] = *(const bf16x8*)&QR[(size_t)qrow * (NH * ROPE) + h * ROPE + (kk - 4) * 32 + quad * 8];
    }

    bf16x8 ones;
    #pragma unroll
    for (int i = 0; i < 8; ++i) ones[i] = (bf16_t)1.0f;

    f32x4 o[8];
    #pragma unroll
    for (int nt = 0; nt < 8; ++nt) o[nt] = (f32x4){0.f, 0.f, 0.f, 0.f};
    f32x4 lacc = (f32x4){0.f, 0.f, 0.f, 0.f};

    for (int kt = kt0; kt < kt1; ++kt) {
        int kbase = kt * 64;
        // stage K: 64 rows x 192 bf16
        #pragma unroll
        for (int l = 0; l < 6; ++l) {
            int cid = tid + l * 256;
            int row = cid / 24, ch = cid % 24;
            uint4 v;
            if (ch < 16) v = *(const uint4*)&KVU[(size_t)(kbase + row) * (NH * 256) + h * 256 + ch * 8];
            else         v = *(const uint4*)&KR[(size_t)(kbase + row) * ROPE + (ch - 16) * 8];
            *(uint4*)&Ks[row * KS_STRIDE + ch * 8] = v;
        }
        __syncthreads();

        // S = Q K^T : 4 col-tiles x 6 k-steps
        f32x4 S[4];
        #pragma unroll
        for (int c = 0; c < 4; ++c) S[c] = (f32x4){0.f, 0.f, 0.f, 0.f};
        #pragma unroll
        for (int kk = 0; kk < 6; ++kk) {
            #pragma unroll
            for (int c = 0; c < 4; ++c) {
                bf16x8 kf = *(const bf16x8*)&Ks[(c * 16 + l16) * KS_STRIDE + kk * 32 + quad * 8];
                S[c] = __builtin_amdgcn_mfma_f32_16x16x32_bf16(qf[kk], kf, S[c], 0, 0, 0);
            }
        }

        // fixed-max softmax: p = exp(s*SCALE) (bounded; shift-invariance -> additive splits)
        #pragma unroll
        for (int c = 0; c < 4; ++c) {
            #pragma unroll
            for (int j = 0; j < 4; ++j) {
                int col = kbase + c * 16 + l16;
                int grow = qbase + w * 16 + quad * 4 + j;
                float p = (col <= grow) ? __expf(S[c][j] * SCALE) : 0.f;
                Ps[w][(quad * 4 + j) * P_STRIDE + c * 16 + l16] = (bf16_t)p;
            }
        }
        __asm__ volatile("s_waitcnt lgkmcnt(0)" ::: "memory");

        bf16x8 pf0 = *(const bf16x8*)&Ps[w][l16 * P_STRIDE + quad * 8];
        bf16x8 pf1 = *(const bf16x8*)&Ps[w][l16 * P_STRIDE + 32 + quad * 8];
        lacc = __builtin_amdgcn_mfma_f32_16x16x32_bf16(pf0, ones, lacc, 0, 0, 0);
        lacc = __builtin_amdgcn_mfma_f32_16x16x32_bf16(pf1, ones, lacc, 0, 0, 0);

        // O += P V : V fragments direct from global vt[h][d][t]
        #pragma unroll
        for (int kk2 = 0; kk2 < 2; ++kk2) {
            bf16x8 pf = kk2 ? pf1 : pf0;
            #pragma unroll
            for (int nt = 0; nt < 8; ++nt) {
                bf16x8 vf = *(const bf16x8*)&Vt[((size_t)h * VDIM + nt * 16 + l16) * T_SEQ + kbase + kk2 * 32 + quad * 8];
                o[nt] = __builtin_amdgcn_mfma_f32_16x16x32_bf16(pf, vf, o[nt], 0, 0, 0);
            }
        }
        __syncthreads();   // protect Ks before restage
    }

    // write raw partials (no normalization)
    #pragma unroll
    for (int nt = 0; nt < 8; ++nt)
        #pragma unroll
        for (int j = 0; j < 4; ++j)
            Opart[(size_t)slot * 8192 + (w * 16 + quad * 4 + j) * 128 + nt * 16 + l16] = (bf16_t)o[nt][j];
    if (l16 == 0) {
        #pragma unroll
        for (int j = 0; j < 4; ++j)
            lpart[slot * 64 + w * 16 + quad * 4 + j] = lacc[j];
    }
}

// ---------------- combine: sum partials, normalize, write ao ----------------
// grid (48, 16), block 256. Thread: row r = tid/4, 32 cols starting (tid%4)*32.
__global__ __launch_bounds__(256) void attn_combine(
    const bf16_t* __restrict__ Opart, const float* __restrict__ lpart,
    bf16_t* __restrict__ AO)
{
    int qt = blockIdx.x, h = blockIdx.y;
    int nch = qt / CHUNK + 1;
    int base = slot_base(qt, h);
    int r = threadIdx.x >> 2, c0 = (threadIdx.x & 3) * 32;

    float acc[32];
    #pragma unroll
    for (int i = 0; i < 32; ++i) acc[i] = 0.f;
    float lsum = 0.f;
    for (int ch = 0; ch < nch; ++ch) {
        int slot = base + ch;
        const bf16_t* p = &Opart[(size_t)slot * 8192 + r * 128 + c0];
        #pragma unroll
        for (int v = 0; v < 4; ++v) {
            bf16x8 u = *(const bf16x8*)&p[v * 8];
            #pragma unroll
            for (int e = 0; e < 8; ++e) acc[v * 8 + e] += (float)u[e];
        }
        lsum += lpart[slot * 64 + r];
    }
    float inv = 1.0f / lsum;
    bf16_t* dst = AO + (size_t)(qt * 64 + r) * (NH * VDIM) + h * VDIM + c0;
    #pragma unroll
    for (int v = 0; v < 4; ++v) {
        bf16_t tmp[8];
        #pragma unroll
        for (int e = 0; e < 8; ++e) tmp[e] = (bf16_t)(acc[v * 8 + e] * inv);
        *(uint4*)&dst[v * 8] = *(const uint4*)tmp;
    }
}

// ---------------- launch ----------------
extern "C" void kernel_launch(void* const* d_in, const int* in_sizes, int n_in,
                              void* d_out, int out_size, void* d_ws, size_t ws_size,
                              hipStream_t stream) {
    const float* x        = (const float*)d_in[0];
    const float* freqs    = (const float*)d_in[1];
    // d_in[2] = mask (unused; causality applied analytically)
    const float* wq_down  = (const float*)d_in[3];
    const float* q_norm_w = (const float*)d_in[4];
    const float* wq_nope  = (const float*)d_in[5];
    const float* wq_rope  = (const float*)d_in[6];
    const float* wkv_down = (const float*)d_in[7];
    const float* kv_norm_w= (const float*)d_in[8];
    const float* wkv_up   = (const float*)d_in[9];
    const float* wo       = (const float*)d_in[10];
    float* out = (float*)d_out;

    bf16_t* ws = (bf16_t*)d_ws;
    // ---- pool region (two time-disjoint views), 25,493,504 bf16 elems ----
    // A-view: pre-attention transients
    bf16_t* xb     = ws;                     // 3072*2048
    bf16_t* wqd_t  = xb     + 6291456;       // [1536][2048]
    bf16_t* wkvd_t = wqd_t  + 3145728;       // [576][2048]
    bf16_t* wqn_t  = wkvd_t + 1179648;       // [2048][1536]
    bf16_t* wqr_t  = wqn_t  + 3145728;       // [1024][1536]
    bf16_t* wkvu_t = wqr_t  + 1572864;       // [4096][512]
    bf16_t* t1     = wkvu_t + 2097152;       // 3072*1536 (q_lat)
    bf16_t* kvd    = t1     + 4718592;       // 3072*576
    bf16_t* ckvn   = kvd    + 1769472;       // 3072*512  (ends at 25,493,504)
    // B-view: attention partials + ao (22,265,856 elems <= pool size)
    bf16_t* Opart  = ws;                     // 1920 slots * 8192
    float*  lpart  = (float*)(ws + 15728640);// 1920 * 64 fp32
    bf16_t* ao     = ws + 15728640 + 245760; // 3072*2048
    // ---- tail region (long-lived) ----
    bf16_t* wo_t   = ws    + 25493504;       // [2048][2048]
    bf16_t* kr     = wo_t  + 4194304;        // 3072*64
    bf16_t* qn     = kr    + 196608;         // 3072*2048
    bf16_t* qr     = qn    + 6291456;        // 3072*1024
    bf16_t* kvu    = qr    + 3145728;        // 3072*4096
    bf16_t* vt     = kvu   + 12582912;       // [16][128][3072]  (total 58,195,968)

    // converts + weight transposes
    f2b_kernel<<<T_SEQ * DIM / 4 / 256, 256, 0, stream>>>(x, xb, T_SEQ * DIM);
    transp_kernel<<<dim3(QLORA / 32, DIM / 32), 256, 0, stream>>>(wq_down, wqd_t, DIM, QLORA);
    transp_kernel<<<dim3((KVLORA + ROPE) / 32, DIM / 32), 256, 0, stream>>>(wkv_down, wkvd_t, DIM, KVLORA + ROPE);
    transp_kernel<<<dim3(NH * NOPE / 32, QLORA / 32), 256, 0, stream>>>(wq_nope, wqn_t, QLORA, NH * NOPE);
    transp_kernel<<<dim3(NH * ROPE / 32, QLORA / 32), 256, 0, stream>>>(wq_rope, wqr_t, QLORA, NH * ROPE);
    transp_kernel<<<dim3(NH * 256 / 32, KVLORA / 32), 256, 0, stream>>>(wkv_up, wkvu_t, KVLORA, NH * 256);
    transp_kernel<<<dim3(DIM / 32, DIM / 32), 256, 0, stream>>>(wo, wo_t, DIM, DIM);

    // down-projections
    gemm_mfma<<<dim3(QLORA / 128, T_SEQ / 128), 256, 0, stream>>>(xb, wqd_t, nullptr, t1, T_SEQ, QLORA, DIM, 0);
    gemm_mfma<<<dim3(5, T_SEQ / 128), 256, 0, stream>>>(xb, wkvd_t, nullptr, kvd, T_SEQ, KVLORA + ROPE, DIM, 0);

    rmsnorm_rows<<<T_SEQ, 256, 0, stream>>>(t1, q_norm_w, QLORA);
    kv_post<<<T_SEQ, 256, 0, stream>>>(kvd, kv_norm_w, freqs, ckvn, kr);

    // up-projections
    gemm_mfma<<<dim3(NH * NOPE / 128, T_SEQ / 128), 256, 0, stream>>>(t1, wqn_t, nullptr, qn, T_SEQ, NH * NOPE, QLORA, 0);
    gemm_mfma<<<dim3(NH * ROPE / 128, T_SEQ / 128), 256, 0, stream>>>(t1, wqr_t, nullptr, qr, T_SEQ, NH * ROPE, QLORA, 0);
    rope_q<<<(T_SEQ * NH * 32 + 255) / 256, 256, 0, stream>>>(qr, freqs);
    gemm_mfma<<<dim3(NH * 256 / 128, T_SEQ / 128), 256, 0, stream>>>(ckvn, wkvu_t, nullptr, kvu, T_SEQ, NH * 256, KVLORA, 0);

    // V transpose for attention B-operand
    vt_transp<<<dim3(T_SEQ / 32, VDIM / 32, NH), 256, 0, stream>>>(kvu, vt);

    // split-K attention + combine
    attn_v4<<<dim3(T_SEQ / 64, 4, NH), 256, 0, stream>>>(qn, qr, kvu, kr, vt, Opart, lpart);
    attn_combine<<<dim3(T_SEQ / 64, NH), 256, 0, stream>>>(Opart, lpart, ao);

    // output projection (fp32 out)
    gemm_mfma<<<dim3(DIM / 128, T_SEQ / 128), 256, 0, stream>>>(ao, wo_t, out, nullptr, T_SEQ, DIM, DIM, 1);
}